// Round 8
// baseline (122.973 us; speedup 1.0000x reference)
//
#include <hip/hip_runtime.h>
#include <math.h>

namespace {
constexpr int kB = 256;
constexpr int kT = 64;
constexpr int kPhys = 3;
constexpr int kLat = 8;
constexpr int kNN = 128;
constexpr int kWin = 32;
constexpr int kPred = 64;
constexpr int kHRow = 132;        // padded f32 activation row
constexpr int kThreads = 512;     // 8 waves; low LDS -> 2-3 blocks/CU
constexpr int kWUnit = 8 * 4 * 64 * 8;  // 16384 shorts per weight plane-unit
}

typedef short bf16x8 __attribute__((ext_vector_type(8)));
typedef float f32x4 __attribute__((ext_vector_type(4)));

__device__ __forceinline__ double rdlane_f64(double x, int l) {
  const long long v = __double_as_longlong(x);
  const int lo = __builtin_amdgcn_readlane((int)(unsigned int)(v & 0xffffffffll), l);
  const int hi = __builtin_amdgcn_readlane((int)(v >> 32), l);
  const long long r = (((long long)hi) << 32) | (unsigned long long)(unsigned int)lo;
  return __longlong_as_double(r);
}

__device__ __forceinline__ unsigned rneb(float f) {  // f32 -> bf16 bits (RNE)
  const unsigned u = __float_as_uint(f);
  return (u + 0x7fffu + ((u >> 16) & 1u)) >> 16;
}
__device__ __forceinline__ void split3(float a, short& s1, short& s2, short& s3) {
  const unsigned b1 = rneb(a);
  const float f1 = __uint_as_float(b1 << 16);
  const float r1 = a - f1;
  const unsigned b2 = rneb(r1);
  const float f2 = __uint_as_float(b2 << 16);
  s1 = (short)b1; s2 = (short)b2; s3 = (short)rneb(r1 - f2);
}
__device__ __forceinline__ void split2(float a, short& s1, short& s2) {
  const unsigned b1 = rneb(a);
  const float f1 = __uint_as_float(b1 << 16);
  s1 = (short)b1; s2 = (short)rneb(a - f1);
}

// ---- prologue: split hidden weights into B-fragment planes (launch-invariant) ----
__global__ __launch_bounds__(256) void split_weights_kernel(
    const float* __restrict__ ewh, const float* __restrict__ dwh,
    short* __restrict__ wfrag)
{
  const int gid = blockIdx.x * 256 + threadIdx.x;  // 12288
  const int l = gid & 63;
  const int q = (gid >> 6) & 3;
  const int n = (gid >> 8) & 7;
  const int layer = gid >> 11;  // 0..5
  const bool enc = layer < 3;
  const float* __restrict__ W = enc ? (ewh + (size_t)layer * kNN * kNN)
                                    : (dwh + (size_t)(layer - 3) * kNN * kNN);
  const int colg = 16 * n + (l & 15);
  const int krow = 8 * (l >> 4);
  bf16x8 p1, p2, p3;
#pragma unroll
  for (int e = 0; e < 8; ++e) {
    const float wv = W[(32 * q + krow + e) * kNN + colg];
    short s1, s2, s3; split3(wv, s1, s2, s3);
    p1[e] = s1; p2[e] = s2; p3[e] = s3;
  }
  const int off = ((n * 4 + q) * 64 + l) * 8;
  if (enc) {
    const size_t base = (size_t)(layer * 3) * kWUnit;
    *(bf16x8*)&wfrag[base + off] = p1;
    *(bf16x8*)&wfrag[base + kWUnit + off] = p2;
    *(bf16x8*)&wfrag[base + 2 * kWUnit + off] = p3;
  } else {
    const size_t base = (size_t)(9 + (layer - 3) * 2) * kWUnit;
    *(bf16x8*)&wfrag[base + off] = p1;
    *(bf16x8*)&wfrag[base + kWUnit + off] = p2;
  }
}

// ---- pack: hb chunk (natural f32 [rows][132]) -> A-fragment planes ----
template<int MT, int SPLITS>
__device__ __forceinline__ void pack_frag(const float* __restrict__ hb,
                                          short* __restrict__ frag, int tid)
{
  constexpr int PLANE = MT * 4 * 64 * 8;
  for (int idx = tid; idx < MT * 256; idx += kThreads) {
    const int m = idx >> 8, q = (idx >> 6) & 3, l = idx & 63;
    const int row = 16 * m + (l & 15), col = 32 * q + 8 * (l >> 4);
    const float4 f0 = *(const float4*)&hb[row * kHRow + col];
    const float4 f1 = *(const float4*)&hb[row * kHRow + col + 4];
    const float f[8] = {f0.x, f0.y, f0.z, f0.w, f1.x, f1.y, f1.z, f1.w};
    bf16x8 p1, p2, p3;
#pragma unroll
    for (int e = 0; e < 8; ++e) {
      if constexpr (SPLITS == 3) {
        short s1, s2, s3; split3(f[e], s1, s2, s3);
        p1[e] = s1; p2[e] = s2; p3[e] = s3;
      } else {
        short s1, s2; split2(f[e], s1, s2);
        p1[e] = s1; p2[e] = s2;
      }
    }
    const int o = ((m * 4 + q) * 64 + l) * 8;
    *(bf16x8*)&frag[o] = p1;
    *(bf16x8*)&frag[PLANE + o] = p2;
    if constexpr (SPLITS == 3) *(bf16x8*)&frag[2 * PLANE + o] = p3;
  }
}

// ---- one hidden-layer chunk (MT m-tiles) via MFMA; all waves on N-tiles ----
template<int MT, int SPLITS>
__device__ __forceinline__ void mfma_layer(
    const short* __restrict__ Bfrag, const float* __restrict__ bias,
    const short* __restrict__ frag, float* __restrict__ hb, int tid)
{
  constexpr int PLANE = MT * 4 * 64 * 8;
  const int n = (tid >> 6) & 7, l = tid & 63;
  const int colg = 16 * n + (l & 15);
  bf16x8 B1[4], B2[4], B3[4];
#pragma unroll
  for (int q = 0; q < 4; ++q) {
    const int boff = ((n * 4 + q) * 64 + l) * 8;
    B1[q] = *(const bf16x8*)&Bfrag[boff];
    B2[q] = *(const bf16x8*)&Bfrag[kWUnit + boff];
    if constexpr (SPLITS == 3) B3[q] = *(const bf16x8*)&Bfrag[2 * kWUnit + boff];
  }
  const float bj = bias[colg];
  f32x4 acc[MT];
#pragma unroll
  for (int mi = 0; mi < MT; ++mi) acc[mi] = {bj, bj, bj, bj};
#pragma unroll
  for (int q = 0; q < 4; ++q) {
#pragma unroll
    for (int mi = 0; mi < MT; ++mi) {
      const int o = ((mi * 4 + q) * 64 + l) * 8;
      const bf16x8 a1 = *(const bf16x8*)&frag[o];
      const bf16x8 a2 = *(const bf16x8*)&frag[PLANE + o];
      acc[mi] = __builtin_amdgcn_mfma_f32_16x16x32_bf16(a1, B1[q], acc[mi], 0, 0, 0);
      acc[mi] = __builtin_amdgcn_mfma_f32_16x16x32_bf16(a1, B2[q], acc[mi], 0, 0, 0);
      acc[mi] = __builtin_amdgcn_mfma_f32_16x16x32_bf16(a2, B1[q], acc[mi], 0, 0, 0);
      if constexpr (SPLITS == 3) {
        const bf16x8 a3 = *(const bf16x8*)&frag[2 * PLANE + o];
        acc[mi] = __builtin_amdgcn_mfma_f32_16x16x32_bf16(a1, B3[q], acc[mi], 0, 0, 0);
        acc[mi] = __builtin_amdgcn_mfma_f32_16x16x32_bf16(a2, B2[q], acc[mi], 0, 0, 0);
        acc[mi] = __builtin_amdgcn_mfma_f32_16x16x32_bf16(a3, B1[q], acc[mi], 0, 0, 0);
      }
    }
  }
  const int rbase = (l >> 4) * 4;
#pragma unroll
  for (int mi = 0; mi < MT; ++mi)
#pragma unroll
    for (int r = 0; r < 4; ++r)
      hb[(16 * mi + rbase + r) * kHRow + colg] = fmaxf(acc[mi][r], 0.f);
}

__global__ __launch_bounds__(kThreads, 4) void fused_kernel(
    const float* __restrict__ x,
    const float* __restrict__ ewin, const float* __restrict__ ebin,
    const float* __restrict__ ebh,
    const float* __restrict__ ewout,const float* __restrict__ ebout,
    const float* __restrict__ dwin, const float* __restrict__ dbin,
    const float* __restrict__ dbh,
    const float* __restrict__ dwout,const float* __restrict__ dbout,
    const short* __restrict__ wfrag,
    float* __restrict__ y_g, float* __restrict__ xae_g,
    float* __restrict__ xadv_g, float* __restrict__ yadv_g)
{
  // union scratch: enc chunk {hb 32x132 f32 (16896) | frag 3x8192B} = 41472
  //                dec chunk {hb 48x132 f32 (25344) | frag 2x12288B} = 49920
  //                DMD f64 scratch = 46392
  __shared__ __align__(16) char US[49920];
  __shared__ float ybuf[kT * kLat];       // 2048 B (persistent y)
  __shared__ float yadv2[kWin * kLat];    // 1024 B (new y_adv rows)
  __shared__ float inb[kT][4];            // 1024 B

  const int tid = threadIdx.x;
  const int b = blockIdx.x;

  double* dmd  = (double*)US;
  double* yd   = dmd;           // [8][65]
  double* P    = dmd + 520;     // [32][67]
  double* Corr = dmd + 2664;    // [32][33]
  double* KTm  = dmd + 3720;    // [31][33]
  double* Dv   = dmd + 4743;    // [32][33]

  // ---- load x ----
  const float* __restrict__ xg = x + (size_t)b * kT * kPhys;
  for (int i = tid; i < kT * kPhys; i += kThreads) inb[i / 3][i % 3] = xg[i];
  __syncthreads();

  // =============== ENCODER: 2 chunks of 32 rows ===============
  {
    float* hb = (float*)US;                    // [32][132]
    short* frag = (short*)(US + 16896);        // 3 planes x 4096 shorts
    for (int ch = 0; ch < 2; ++ch) {
      const int r0 = ch * 32;
      // input layer 3 -> 128 (rows r0..r0+31)
      {
        const int j = tid & 127, rg = tid >> 7;  // rg 0..3, 8 rows each
        const float w0 = ewin[j], w1 = ewin[kNN + j], w2 = ewin[2 * kNN + j];
        const float bj = ebin[j];
#pragma unroll
        for (int rr = 0; rr < 8; ++rr) {
          const int r = rg * 8 + rr;
          const int gr = r0 + r;
          hb[r * kHRow + j] =
              fmaxf(bj + inb[gr][0] * w0 + inb[gr][1] * w1 + inb[gr][2] * w2, 0.f);
        }
      }
      __syncthreads();
      // 3 hidden layers, 3-split (f32-exact)
#pragma unroll
      for (int L = 0; L < 3; ++L) {
        pack_frag<2, 3>(hb, frag, tid);
        __syncthreads();
        mfma_layer<2, 3>(wfrag + (size_t)(L * 3) * kWUnit, ebh + L * kNN, frag, hb, tid);
        __syncthreads();
      }
      // output layer 128 -> 8
      if (tid < 256) {
        const int r = tid >> 3, o = tid & 7;
        float a = ebout[o];
        for (int k4 = 0; k4 < kNN; k4 += 4) {
          const float4 hv = *(const float4*)&hb[r * kHRow + k4];
          a += hv.x * ewout[(k4 + 0) * kLat + o] + hv.y * ewout[(k4 + 1) * kLat + o]
             + hv.z * ewout[(k4 + 2) * kLat + o] + hv.w * ewout[(k4 + 3) * kLat + o];
        }
        ybuf[(r0 + r) * kLat + o] = a;
        y_g[(size_t)b * kT * kLat + (r0 + r) * kLat + o] = a;
      }
      __syncthreads();
    }
  }

  // ---- fill yd (f64) from ybuf; US now owned by DMD ----
  {
    const int r = tid >> 3, o = tid & 7;  // 512 = 64*8
    yd[o * 65 + r] = (double)ybuf[r * kLat + o];
  }
  __syncthreads();

  // =============== Hankel-DMD (f64, exact-math rewrite) ===============
  {
    for (int idx = tid; idx < 32 * 64; idx += kThreads) {
      const int d = idx >> 6, t = idx & 63;
      if (t + d < kT) {
        double s = 0.0;
#pragma unroll
        for (int l = 0; l < kLat; ++l) s += yd[l * 65 + t] * yd[l * 65 + t + d];
        P[d * 67 + t] = s;
      }
    }
    __syncthreads();

    for (int idx = tid; idx < 32 * 32; idx += kThreads) {
      const int a = idx >> 5, c = idx & 31;
      const int d = (c >= a) ? (c - a) : (a - c);
      const int base = (c >= a) ? a : c;
      double s0 = 0.0, s1 = 0.0;
#pragma unroll
      for (int r = 0; r < 32; r += 2) { s0 += P[d * 67 + base + r]; s1 += P[d * 67 + base + r + 1]; }
      Corr[a * 33 + c] = s0 + s1 + P[d * 67 + base + 32];
    }
    __syncthreads();

    // single-wave register Gauss-Jordan [G|C] -> [I|K], then power iteration
    if (tid < 64) {
      const int lane = tid;
      const int colidx = (lane <= 30) ? lane : (lane <= 61 ? lane - 30 : 1);
      double m[31];
#pragma unroll
      for (int i = 0; i < 31; ++i) m[i] = Corr[i * 33 + colidx];
#pragma unroll
      for (int k = 0; k < 31; ++k) {
        const double piv = rdlane_f64(m[k], k);
        const double pinv = 1.0 / piv;
        m[k] *= pinv;
#pragma unroll
        for (int i = 0; i < 31; ++i) {
          if (i == k) continue;
          const double bci = rdlane_f64(m[i], k);
          m[i] = fma(-bci, m[k], m[i]);
        }
      }
      if (lane >= 31 && lane < 62) {
        const int c = lane - 31;
#pragma unroll
        for (int i = 0; i < 31; ++i) KTm[i * 33 + c] = m[i];
      }
      const int ri = (lane < 31) ? lane : 0;
      double Kr[31];
#pragma unroll
      for (int j = 0; j < 31; ++j) Kr[j] = KTm[ri * 33 + j];

      double dv = Kr[30];  // d_0 = K[:,30]
      if (lane < 31) Dv[0 * 33 + lane] = dv;
      for (int k = 0; k < 31; ++k) {
        double a0 = 0.0, a1 = 0.0, a2 = 0.0, a3 = 0.0;
#pragma unroll
        for (int j = 0; j < 31; ++j) {
          const double dj = rdlane_f64(dv, j);
          if ((j & 3) == 0) a0 = fma(Kr[j], dj, a0);
          else if ((j & 3) == 1) a1 = fma(Kr[j], dj, a1);
          else if ((j & 3) == 2) a2 = fma(Kr[j], dj, a2);
          else a3 = fma(Kr[j], dj, a3);
        }
        dv = (a0 + a1) + (a2 + a3);
        if (lane < 31) Dv[(k + 1) * 33 + lane] = dv;
      }
    }
    __syncthreads();

    float* __restrict__ ob = yadv_g + (size_t)b * kPred * kLat;
    if (tid < 256) {
      ob[tid] = ybuf[tid];  // p < 32: exact copy of y
    } else {
      const int q = tid - 256;
      const int k = q >> 3, l = q & 7;
      double a0 = 0.0, a1 = 0.0, a2 = 0.0, a3 = 0.0;
#pragma unroll
      for (int j = 0; j < 31; ++j) {
        const double t = yd[l * 65 + j + 1];
        if ((j & 3) == 0) a0 = fma(t, Dv[k * 33 + j], a0);
        else if ((j & 3) == 1) a1 = fma(t, Dv[k * 33 + j], a1);
        else if ((j & 3) == 2) a2 = fma(t, Dv[k * 33 + j], a2);
        else a3 = fma(t, Dv[k * 33 + j], a3);
      }
      const float v = (float)((a0 + a1) + (a2 + a3));
      ob[256 + q] = v;
      yadv2[q] = v;
    }
    __syncthreads();  // yd/Dv dead; US free for decoder
  }

  // =============== DECODER: 2 chunks of 48 rows (96 total) ===============
  {
    float* hb = (float*)US;                    // [48][132]
    short* frag = (short*)(US + 25344);        // 2 planes x 12288 shorts
    for (int ch = 0; ch < 2; ++ch) {
      const int R0 = ch * 48;
      // input layer 8 -> 128 (rows R0..R0+47; rows >=64 come from yadv2)
      {
        const int j = tid & 127, rg = tid >> 7;  // 12 rows each
        float wr[kLat];
#pragma unroll
        for (int k = 0; k < kLat; ++k) wr[k] = dwin[k * kNN + j];
        const float bj = dbin[j];
#pragma unroll
        for (int rr = 0; rr < 12; ++rr) {
          const int r = rg * 12 + rr;
          const int gr = R0 + r;
          const float* __restrict__ src =
              (gr < kT) ? &ybuf[gr * kLat] : &yadv2[(gr - kT) * kLat];
          float a = bj;
#pragma unroll
          for (int k = 0; k < kLat; ++k) a += src[k] * wr[k];
          hb[r * kHRow + j] = fmaxf(a, 0.f);
        }
      }
      __syncthreads();
      // 3 hidden layers, 2-split (terminal path)
#pragma unroll
      for (int L = 0; L < 3; ++L) {
        pack_frag<3, 2>(hb, frag, tid);
        __syncthreads();
        mfma_layer<3, 2>(wfrag + (size_t)(9 + L * 2) * kWUnit, dbh + L * kNN, frag, hb, tid);
        __syncthreads();
      }
      // output layer 128 -> 3
      if (tid < 144) {
        const int r = tid / 3, o = tid - r * 3;
        const int gr = R0 + r;
        float a = dbout[o];
        for (int k4 = 0; k4 < kNN; k4 += 4) {
          const float4 hv = *(const float4*)&hb[r * kHRow + k4];
          a += hv.x * dwout[(k4 + 0) * kPhys + o] + hv.y * dwout[(k4 + 1) * kPhys + o]
             + hv.z * dwout[(k4 + 2) * kPhys + o] + hv.w * dwout[(k4 + 3) * kPhys + o];
        }
        if (gr < kT) {
          xae_g[(size_t)b * kT * kPhys + gr * kPhys + o] = a;
          if (gr < kWin) xadv_g[(size_t)b * kT * kPhys + gr * kPhys + o] = a;
        } else {
          const int rr = gr - kT + kWin;  // 32..63
          xadv_g[(size_t)b * kT * kPhys + rr * kPhys + o] = a;
        }
      }
      __syncthreads();
    }
  }
}

extern "C" void kernel_launch(void* const* d_in, const int* in_sizes, int n_in,
                              void* d_out, int out_size, void* d_ws, size_t ws_size,
                              hipStream_t stream)
{
  const float* x         = (const float*)d_in[0];
  const float* enc_w_in  = (const float*)d_in[1];
  const float* enc_b_in  = (const float*)d_in[2];
  const float* enc_w_h   = (const float*)d_in[3];
  const float* enc_b_h   = (const float*)d_in[4];
  const float* enc_w_out = (const float*)d_in[5];
  const float* enc_b_out = (const float*)d_in[6];
  const float* dec_w_in  = (const float*)d_in[7];
  const float* dec_b_in  = (const float*)d_in[8];
  const float* dec_w_h   = (const float*)d_in[9];
  const float* dec_b_h   = (const float*)d_in[10];
  const float* dec_w_out = (const float*)d_in[11];
  const float* dec_b_out = (const float*)d_in[12];

  float* out   = (float*)d_out;
  float* y     = out;                                  // (B,T,8)   131072
  float* x_ae  = out + (size_t)kB * kT * kLat;         // (B,T,3)    49152
  float* x_adv = x_ae + (size_t)kB * kT * kPhys;       // (B,T,3)    49152
  float* y_adv = x_adv + (size_t)kB * kT * kPhys;      // (B,64,8)  131072

  short* wfrag = (short*)d_ws;   // 15 units x 16384 shorts = 491520 B

  split_weights_kernel<<<48, 256, 0, stream>>>(enc_w_h, dec_w_h, wfrag);
  fused_kernel<<<kB, kThreads, 0, stream>>>(
      x, enc_w_in, enc_b_in, enc_b_h, enc_w_out, enc_b_out,
      dec_w_in, dec_b_in, dec_b_h, dec_w_out, dec_b_out,
      wfrag, y, x_ae, x_adv, y_adv);
}

// Round 9
// 55.895 us; speedup vs baseline: 2.2001x; 2.2001x over previous
//
#include <hip/hip_runtime.h>
#include <math.h>

namespace {
constexpr int kB = 256;
constexpr int kT = 64;
constexpr int kPhys = 3;
constexpr int kLat = 8;
constexpr int kNN = 128;
constexpr int kWin = 32;
constexpr int kPred = 64;
constexpr int kHRow = 132;        // padded f32 activation row
constexpr int kThreads = 1024;
constexpr int kWUnit = 8 * 4 * 64 * 8;  // 16384 shorts per weight plane-unit
constexpr int kUS = 50688;        // union scratch size (bytes)
}

typedef short bf16x8 __attribute__((ext_vector_type(8)));
typedef float f32x4 __attribute__((ext_vector_type(4)));

__device__ __forceinline__ double rdlane_f64(double x, int l) {
  const long long v = __double_as_longlong(x);
  const int lo = __builtin_amdgcn_readlane((int)(unsigned int)(v & 0xffffffffll), l);
  const int hi = __builtin_amdgcn_readlane((int)(v >> 32), l);
  const long long r = (((long long)hi) << 32) | (unsigned long long)(unsigned int)lo;
  return __longlong_as_double(r);
}

__device__ __forceinline__ unsigned rneb(float f) {  // f32 -> bf16 bits (RNE)
  const unsigned u = __float_as_uint(f);
  return (u + 0x7fffu + ((u >> 16) & 1u)) >> 16;
}
__device__ __forceinline__ void split3(float a, short& s1, short& s2, short& s3) {
  const unsigned b1 = rneb(a);
  const float f1 = __uint_as_float(b1 << 16);
  const float r1 = a - f1;
  const unsigned b2 = rneb(r1);
  const float f2 = __uint_as_float(b2 << 16);
  s1 = (short)b1; s2 = (short)b2; s3 = (short)rneb(r1 - f2);
}
__device__ __forceinline__ void split2(float a, short& s1, short& s2) {
  const unsigned b1 = rneb(a);
  const float f1 = __uint_as_float(b1 << 16);
  s1 = (short)b1; s2 = (short)rneb(a - f1);
}

// ---- prologue: split hidden weights into B-fragment planes (launch-invariant) ----
__global__ __launch_bounds__(256) void split_weights_kernel(
    const float* __restrict__ ewh, const float* __restrict__ dwh,
    short* __restrict__ wfrag)
{
  const int gid = blockIdx.x * 256 + threadIdx.x;  // 12288
  const int l = gid & 63;
  const int q = (gid >> 6) & 3;
  const int n = (gid >> 8) & 7;
  const int layer = gid >> 11;  // 0..5
  const bool enc = layer < 3;
  const float* __restrict__ W = enc ? (ewh + (size_t)layer * kNN * kNN)
                                    : (dwh + (size_t)(layer - 3) * kNN * kNN);
  const int colg = 16 * n + (l & 15);
  const int krow = 8 * (l >> 4);
  bf16x8 p1, p2, p3;
#pragma unroll
  for (int e = 0; e < 8; ++e) {
    const float wv = W[(32 * q + krow + e) * kNN + colg];
    short s1, s2, s3; split3(wv, s1, s2, s3);
    p1[e] = s1; p2[e] = s2; p3[e] = s3;
  }
  const int off = ((n * 4 + q) * 64 + l) * 8;
  if (enc) {
    const size_t base = (size_t)(layer * 3) * kWUnit;
    *(bf16x8*)&wfrag[base + off] = p1;
    *(bf16x8*)&wfrag[base + kWUnit + off] = p2;
    *(bf16x8*)&wfrag[base + 2 * kWUnit + off] = p3;
  } else {
    const size_t base = (size_t)(9 + (layer - 3) * 2) * kWUnit;
    *(bf16x8*)&wfrag[base + off] = p1;
    *(bf16x8*)&wfrag[base + kWUnit + off] = p2;
  }
}

// ---- one hidden layer 128->128 (+relu) via MFMA; A-frags from fragIn,
//      epilogue scatter-writes next layer's A-frags (or natural f32 hb) ----
template<int MPW, int SPLITS, bool TO_FRAG>
__device__ __forceinline__ void mfma_scatter(
    const short* __restrict__ Bfrag, const float* __restrict__ bias,
    const short* __restrict__ fragIn, void* __restrict__ out, int tid)
{
  constexpr int MT = 2 * MPW;
  constexpr int PLANE = MT * 4 * 64 * 8;
  const int w = tid >> 6, l = tid & 63;
  const int n = w & 7, m0 = (w >> 3) * MPW;
  const int colg = 16 * n + (l & 15);
  bf16x8 B1[4], B2[4], B3[4];
#pragma unroll
  for (int q = 0; q < 4; ++q) {
    const int boff = ((n * 4 + q) * 64 + l) * 8;
    B1[q] = *(const bf16x8*)&Bfrag[boff];
    B2[q] = *(const bf16x8*)&Bfrag[kWUnit + boff];
    if constexpr (SPLITS == 3) B3[q] = *(const bf16x8*)&Bfrag[2 * kWUnit + boff];
  }
  const float bj = bias[colg];
  f32x4 acc[MPW];
#pragma unroll
  for (int mi = 0; mi < MPW; ++mi) acc[mi] = {bj, bj, bj, bj};
#pragma unroll
  for (int q = 0; q < 4; ++q) {
#pragma unroll
    for (int mi = 0; mi < MPW; ++mi) {
      const int o = (((m0 + mi) * 4 + q) * 64 + l) * 8;
      const bf16x8 a1 = *(const bf16x8*)&fragIn[o];
      const bf16x8 a2 = *(const bf16x8*)&fragIn[PLANE + o];
      acc[mi] = __builtin_amdgcn_mfma_f32_16x16x32_bf16(a1, B1[q], acc[mi], 0, 0, 0);
      acc[mi] = __builtin_amdgcn_mfma_f32_16x16x32_bf16(a1, B2[q], acc[mi], 0, 0, 0);
      acc[mi] = __builtin_amdgcn_mfma_f32_16x16x32_bf16(a2, B1[q], acc[mi], 0, 0, 0);
      if constexpr (SPLITS == 3) {
        const bf16x8 a3 = *(const bf16x8*)&fragIn[2 * PLANE + o];
        acc[mi] = __builtin_amdgcn_mfma_f32_16x16x32_bf16(a1, B3[q], acc[mi], 0, 0, 0);
        acc[mi] = __builtin_amdgcn_mfma_f32_16x16x32_bf16(a2, B2[q], acc[mi], 0, 0, 0);
        acc[mi] = __builtin_amdgcn_mfma_f32_16x16x32_bf16(a3, B1[q], acc[mi], 0, 0, 0);
      }
    }
  }
  const int rbase = (l >> 4) * 4;
  if constexpr (TO_FRAG) {
    short* __restrict__ f = (short*)out;
    const int qt = colg >> 5, sub = (colg >> 3) & 3, et = colg & 7;
#pragma unroll
    for (int mi = 0; mi < MPW; ++mi)
#pragma unroll
      for (int r = 0; r < 4; ++r) {
        const float v = fmaxf(acc[mi][r], 0.f);
        const int off = (((m0 + mi) * 4 + qt) * 64 + (rbase + r + 16 * sub)) * 8 + et;
        if constexpr (SPLITS == 3) {
          short s1, s2, s3; split3(v, s1, s2, s3);
          f[off] = s1; f[PLANE + off] = s2; f[2 * PLANE + off] = s3;
        } else {
          short s1, s2; split2(v, s1, s2);
          f[off] = s1; f[PLANE + off] = s2;
        }
      }
  } else {
    float* __restrict__ hb = (float*)out;
#pragma unroll
    for (int mi = 0; mi < MPW; ++mi)
#pragma unroll
      for (int r = 0; r < 4; ++r)
        hb[(16 * (m0 + mi) + rbase + r) * kHRow + colg] = fmaxf(acc[mi][r], 0.f);
  }
}

__global__ __launch_bounds__(kThreads, 4) void fused_kernel(
    const float* __restrict__ x,
    const float* __restrict__ ewin, const float* __restrict__ ebin,
    const float* __restrict__ ebh,
    const float* __restrict__ ewout,const float* __restrict__ ebout,
    const float* __restrict__ dwin, const float* __restrict__ dbin,
    const float* __restrict__ dbh,
    const float* __restrict__ dwout,const float* __restrict__ dbout,
    const short* __restrict__ wfrag,
    float* __restrict__ y_g, float* __restrict__ xae_g,
    float* __restrict__ xadv_g, float* __restrict__ yadv_g)
{
  // US1/US2: frag planes <-> hb f32 <-> DMD f64 scratch (phase-disjoint)
  __shared__ __align__(16) char US1[kUS];
  __shared__ __align__(16) char US2[kUS];
  __shared__ float ybuf[kT * kLat];       // persistent y
  __shared__ float yadv2[kWin * kLat];    // new y_adv rows

  const int tid = threadIdx.x;
  const int b = blockIdx.x;

  double* dmd  = (double*)US1;
  double* yd   = dmd;           // [8][65]
  double* P    = dmd + 520;     // [32][67]
  double* Corr = dmd + 2664;    // [32][33]
  double* KTm  = dmd + 3720;    // [31][33]
  double* Dv   = dmd + 4743;    // [32][33]  (ends 5799 dbl = 46392 B)

  constexpr int PE = 4 * 4 * 64 * 8;   // enc plane (shorts)
  constexpr int PD = 6 * 4 * 64 * 8;   // dec plane (shorts)

  // ---- encoder input layer 3 -> 128, scatter-frag into US1 ----
  {
    short* __restrict__ f = (short*)US1;
    const float* __restrict__ xg = x + (size_t)b * kT * kPhys;
    const int j = tid & 127, rg = tid >> 7;  // 8 rows each
    const float w0 = ewin[j], w1 = ewin[kNN + j], w2 = ewin[2 * kNN + j];
    const float bj = ebin[j];
    const int qt = j >> 5, sub = (j >> 3) & 3, et = j & 7;
#pragma unroll
    for (int rr = 0; rr < 8; ++rr) {
      const int r = rg * 8 + rr;
      const float* __restrict__ xr = xg + r * 3;
      const float a = fmaxf(bj + xr[0] * w0 + xr[1] * w1 + xr[2] * w2, 0.f);
      short s1, s2, s3; split3(a, s1, s2, s3);
      const int off = (((r >> 4) * 4 + qt) * 64 + ((r & 15) + 16 * sub)) * 8 + et;
      f[off] = s1; f[PE + off] = s2; f[2 * PE + off] = s3;
    }
  }
  __syncthreads();

  // ---- encoder hidden layers (3-split, f32-exact): US1->US2->US1->US2(hb) ----
  mfma_scatter<2, 3, true >(wfrag + (size_t)0 * kWUnit, ebh + 0 * kNN, (short*)US1, US2, tid);
  __syncthreads();
  mfma_scatter<2, 3, true >(wfrag + (size_t)3 * kWUnit, ebh + 1 * kNN, (short*)US2, US1, tid);
  __syncthreads();
  mfma_scatter<2, 3, false>(wfrag + (size_t)6 * kWUnit, ebh + 2 * kNN, (short*)US1, US2, tid);
  __syncthreads();

  // ---- encoder output layer 128 -> 8 (reads US2-hb; writes ybuf, y_g, yd->US1) ----
  if (tid < 512) {
    const float* __restrict__ hb = (const float*)US2;
    const int r = tid >> 3, o = tid & 7;
    float a = ebout[o];
    for (int k4 = 0; k4 < kNN; k4 += 4) {
      const float4 hv = *(const float4*)&hb[r * kHRow + k4];
      a += hv.x * ewout[(k4 + 0) * kLat + o] + hv.y * ewout[(k4 + 1) * kLat + o]
         + hv.z * ewout[(k4 + 2) * kLat + o] + hv.w * ewout[(k4 + 3) * kLat + o];
    }
    ybuf[r * kLat + o] = a;
    y_g[(size_t)b * kT * kLat + tid] = a;
    yd[o * 65 + r] = (double)a;
  }
  __syncthreads();

  // =============== Hankel-DMD (f64, exact-math rewrite; scratch US1) ===============
  {
    for (int idx = tid; idx < 32 * 64; idx += kThreads) {
      const int d = idx >> 6, t = idx & 63;
      if (t + d < kT) {
        double s = 0.0;
#pragma unroll
        for (int l = 0; l < kLat; ++l) s += yd[l * 65 + t] * yd[l * 65 + t + d];
        P[d * 67 + t] = s;
      }
    }
    __syncthreads();

    {
      const int a = tid >> 5, c = tid & 31;
      const int d = (c >= a) ? (c - a) : (a - c);
      const int base = (c >= a) ? a : c;
      double s0 = 0.0, s1 = 0.0;
#pragma unroll
      for (int r = 0; r < 32; r += 2) { s0 += P[d * 67 + base + r]; s1 += P[d * 67 + base + r + 1]; }
      Corr[a * 33 + c] = s0 + s1 + P[d * 67 + base + 32];
    }
    __syncthreads();

    // single-wave register Gauss-Jordan [G|C] -> [I|K], then power iteration
    if (tid < 64) {
      const int lane = tid;
      const int colidx = (lane <= 30) ? lane : (lane <= 61 ? lane - 30 : 1);
      double m[31];
#pragma unroll
      for (int i = 0; i < 31; ++i) m[i] = Corr[i * 33 + colidx];
#pragma unroll
      for (int k = 0; k < 31; ++k) {
        const double piv = rdlane_f64(m[k], k);
        const double pinv = 1.0 / piv;
        m[k] *= pinv;
#pragma unroll
        for (int i = 0; i < 31; ++i) {
          if (i == k) continue;
          const double bci = rdlane_f64(m[i], k);
          m[i] = fma(-bci, m[k], m[i]);
        }
      }
      if (lane >= 31 && lane < 62) {
        const int c = lane - 31;
#pragma unroll
        for (int i = 0; i < 31; ++i) KTm[i * 33 + c] = m[i];
      }
      const int ri = (lane < 31) ? lane : 0;
      double Kr[31];
#pragma unroll
      for (int j = 0; j < 31; ++j) Kr[j] = KTm[ri * 33 + j];

      double dv = Kr[30];  // d_0 = K[:,30]
      if (lane < 31) Dv[0 * 33 + lane] = dv;
      for (int k = 0; k < 31; ++k) {
        double a0 = 0.0, a1 = 0.0, a2 = 0.0, a3 = 0.0;
#pragma unroll
        for (int j = 0; j < 31; ++j) {
          const double dj = rdlane_f64(dv, j);
          if ((j & 3) == 0) a0 = fma(Kr[j], dj, a0);
          else if ((j & 3) == 1) a1 = fma(Kr[j], dj, a1);
          else if ((j & 3) == 2) a2 = fma(Kr[j], dj, a2);
          else a3 = fma(Kr[j], dj, a3);
        }
        dv = (a0 + a1) + (a2 + a3);
        if (lane < 31) Dv[(k + 1) * 33 + lane] = dv;
      }
    }
    __syncthreads();

    float* __restrict__ ob = yadv_g + (size_t)b * kPred * kLat;
    if (tid < 256) {
      ob[tid] = ybuf[tid];  // p < 32: exact copy of y
    } else if (tid < 512) {
      const int q = tid - 256;
      const int k = q >> 3, l = q & 7;
      double a0 = 0.0, a1 = 0.0, a2 = 0.0, a3 = 0.0;
#pragma unroll
      for (int j = 0; j < 31; ++j) {
        const double t = yd[l * 65 + j + 1];
        if ((j & 3) == 0) a0 = fma(t, Dv[k * 33 + j], a0);
        else if ((j & 3) == 1) a1 = fma(t, Dv[k * 33 + j], a1);
        else if ((j & 3) == 2) a2 = fma(t, Dv[k * 33 + j], a2);
        else a3 = fma(t, Dv[k * 33 + j], a3);
      }
      const float v = (float)((a0 + a1) + (a2 + a3));
      ob[256 + q] = v;
      yadv2[q] = v;
    }
    __syncthreads();  // DMD scratch dead; US1/US2 free for decoder
  }

  // ---- decoder input layer 8 -> 128, 96 rows, scatter-frag into US2 ----
  {
    short* __restrict__ f = (short*)US2;
    const int j = tid & 127, rg = tid >> 7;  // 12 rows each
    float wr[kLat];
#pragma unroll
    for (int k = 0; k < kLat; ++k) wr[k] = dwin[k * kNN + j];
    const float bj = dbin[j];
    const int qt = j >> 5, sub = (j >> 3) & 3, et = j & 7;
#pragma unroll
    for (int rr = 0; rr < 12; ++rr) {
      const int r = rg * 12 + rr;
      const float* __restrict__ src = (r < kT) ? &ybuf[r * kLat] : &yadv2[(r - kT) * kLat];
      float a = bj;
#pragma unroll
      for (int k = 0; k < kLat; ++k) a += src[k] * wr[k];
      a = fmaxf(a, 0.f);
      short s1, s2; split2(a, s1, s2);
      const int off = (((r >> 4) * 4 + qt) * 64 + ((r & 15) + 16 * sub)) * 8 + et;
      f[off] = s1; f[PD + off] = s2;
    }
  }
  __syncthreads();

  // ---- decoder hidden layers (2-split): US2->US1->US2->US1(hb) ----
  mfma_scatter<3, 2, true >(wfrag + (size_t)9  * kWUnit, dbh + 0 * kNN, (short*)US2, US1, tid);
  __syncthreads();
  mfma_scatter<3, 2, true >(wfrag + (size_t)11 * kWUnit, dbh + 1 * kNN, (short*)US1, US2, tid);
  __syncthreads();
  mfma_scatter<3, 2, false>(wfrag + (size_t)13 * kWUnit, dbh + 2 * kNN, (short*)US2, US1, tid);
  __syncthreads();

  // ---- decoder output layer 128 -> 3 (reads US1-hb) ----
  if (tid < 96 * kPhys) {
    const float* __restrict__ hb = (const float*)US1;
    const int r = tid / 3, o = tid - r * 3;
    float a = dbout[o];
    for (int k4 = 0; k4 < kNN; k4 += 4) {
      const float4 hv = *(const float4*)&hb[r * kHRow + k4];
      a += hv.x * dwout[(k4 + 0) * kPhys + o] + hv.y * dwout[(k4 + 1) * kPhys + o]
         + hv.z * dwout[(k4 + 2) * kPhys + o] + hv.w * dwout[(k4 + 3) * kPhys + o];
    }
    if (r < kT) {
      xae_g[(size_t)b * kT * kPhys + tid] = a;
      if (r < kWin) xadv_g[(size_t)b * kT * kPhys + tid] = a;
    } else {
      const int rr = r - kT + kWin;  // 32..63
      xadv_g[(size_t)b * kT * kPhys + rr * kPhys + o] = a;
    }
  }
}

extern "C" void kernel_launch(void* const* d_in, const int* in_sizes, int n_in,
                              void* d_out, int out_size, void* d_ws, size_t ws_size,
                              hipStream_t stream)
{
  const float* x         = (const float*)d_in[0];
  const float* enc_w_in  = (const float*)d_in[1];
  const float* enc_b_in  = (const float*)d_in[2];
  const float* enc_w_h   = (const float*)d_in[3];
  const float* enc_b_h   = (const float*)d_in[4];
  const float* enc_w_out = (const float*)d_in[5];
  const float* enc_b_out = (const float*)d_in[6];
  const float* dec_w_in  = (const float*)d_in[7];
  const float* dec_b_in  = (const float*)d_in[8];
  const float* dec_w_h   = (const float*)d_in[9];
  const float* dec_b_h   = (const float*)d_in[10];
  const float* dec_w_out = (const float*)d_in[11];
  const float* dec_b_out = (const float*)d_in[12];

  float* out   = (float*)d_out;
  float* y     = out;                                  // (B,T,8)   131072
  float* x_ae  = out + (size_t)kB * kT * kLat;         // (B,T,3)    49152
  float* x_adv = x_ae + (size_t)kB * kT * kPhys;       // (B,T,3)    49152
  float* y_adv = x_adv + (size_t)kB * kT * kPhys;      // (B,64,8)  131072

  short* wfrag = (short*)d_ws;   // 15 units x 16384 shorts = 491520 B

  split_weights_kernel<<<48, 256, 0, stream>>>(enc_w_h, dec_w_h, wfrag);
  fused_kernel<<<kB, kThreads, 0, stream>>>(
      x, enc_w_in, enc_b_in, enc_b_h, enc_w_out, enc_b_out,
      dec_w_in, dec_b_in, dec_b_h, dec_w_out, dec_b_out,
      wfrag, y, x_ae, x_adv, y_adv);
}